// Round 8
// baseline (436.570 us; speedup 1.0000x reference)
//
#include <hip/hip_runtime.h>
#include <hip/hip_bf16.h>

#define N_NODES 50000
#define E_EDGES 800000
#define EP_EDGES 850000   // E + N self loops
#define IN_DIM 160
#define HEADS 4
#define HID 64
#define C1 256            // HEADS*HID
#define NEG_SLOPE 0.2f
#define BN_EPS 1e-5f

typedef __attribute__((ext_vector_type(8))) short bf16x8;
typedef __attribute__((ext_vector_type(4))) float f32x4;
typedef __attribute__((ext_vector_type(2))) float f32x2;

__device__ __forceinline__ float b2f(ushort u) {
    return __uint_as_float(((unsigned)u) << 16);
}
__device__ __forceinline__ ushort f2b(float f) {
    __hip_bfloat16 h = __float2bfloat16(f);
    return *reinterpret_cast<ushort*>(&h);
}
__device__ __forceinline__ float lo16(uint u) { return __uint_as_float(u << 16); }
__device__ __forceinline__ float hi16(uint u) { return __uint_as_float(u & 0xffff0000u); }
__device__ __forceinline__ f32x2 unpk(uint u) {
    f32x2 r; r.x = lo16(u); r.y = hi16(u); return r;
}

// DPP-based add of a permuted copy: pure VALU pipe
template<int CTRL>
__device__ __forceinline__ float dpp_add(float p) {
    int t = __builtin_amdgcn_update_dpp(0, __float_as_int(p), CTRL, 0xf, 0xf, true);
    return p + __int_as_float(t);
}
// sum over each 16-lane row; all 16 lanes get the row total
__device__ __forceinline__ float row16_sum(float p) {
    p = dpp_add<0xB1>(p);    // quad_perm xor1
    p = dpp_add<0x4E>(p);    // quad_perm xor2
    p = dpp_add<0x124>(p);   // row_ror:4
    p = dpp_add<0x128>(p);   // row_ror:8
    return p;
}

// ---------------- runtime dtype detection ----------------
// flags[0]: 1 if float tensors are fp32 on device; flags[1]: 1 if edges int64
__global__ void detect_k(const ushort* __restrict__ xraw,
                         const int* __restrict__ eraw,
                         int* __restrict__ flags) {
    int lane = threadIdx.x;  // 64 threads
    int good = 0, nz = 0;
    for (int i = lane; i < 256; i += 64) {
        float a = fabsf(b2f(xraw[2 * i]));
        good += (a > 1e-6f && a < 1e6f) ? 1 : 0;
        nz += (eraw[2 * i + 1] != 0) ? 1 : 0;
    }
    #pragma unroll
    for (int off = 32; off > 0; off >>= 1) {
        good += __shfl_xor(good, off);
        nz += __shfl_xor(nz, off);
    }
    if (lane == 0) {
        flags[0] = (good < 192) ? 1 : 0;
        flags[1] = (nz == 0) ? 1 : 0;
    }
}

// ---------------- canonicalize x -> bf16 (also zeroes deg) ----------------
__global__ void cvt_x_k(const void* __restrict__ src, ushort* __restrict__ dst,
                        const int* __restrict__ flags, int* __restrict__ deg) {
    int i = blockIdx.x * 256 + threadIdx.x;
    if (i < N_NODES) deg[i] = 0;
    if (i >= N_NODES * IN_DIM) return;
    dst[i] = flags[0] ? f2b(((const float*)src)[i]) : ((const ushort*)src)[i];
}

// ---------------- merged: weight swizzle (raw->MFMA frag order) + small-param canonicalize ----------------
struct SW2 {
    const void* W[5];    // raw Wl1, Wr1, Ws, Wl2, Wr2
    ushort* D[5];
    int NT[5];
    int base[5];
    const void* sp[19];  // raw small tensors
};

__global__ void swzp_k(SW2 s, ushort* __restrict__ params,
                       const int* __restrict__ flags) {
    const bool f32 = flags[0] != 0;
    if (blockIdx.x < 61) {
        int idx = blockIdx.x * 256 + threadIdx.x;   // < 15616
        int seg = 0;
        #pragma unroll
        for (int k = 1; k < 5; ++k) seg += (idx >= s.base[k]) ? 1 : 0;
        int li = idx - s.base[seg];
        int NT = s.NT[seg];
        int N = NT << 4;
        int lane = li & 63;
        int ft = li >> 6;
        int kb = ft / NT, t = ft - kb * NT;
        int q = lane >> 4, m = lane & 15;
        const float* pf = (const float*)s.W[seg];
        const ushort* pu = (const ushort*)s.W[seg];
        ushort* d = s.D[seg] + (size_t)li * 8;
        #pragma unroll
        for (int j = 0; j < 8; ++j) {
            size_t src = (size_t)(kb * 32 + q * 8 + j) * N + t * 16 + m;
            d[j] = f32 ? f2b(pf[src]) : pu[src];
        }
    } else {
        const int SZ[19] = {256,256,256,256,256,256,256,256,
                            64,64,64,64,64,64,64,64,64,64, 1};
        const int OF[19] = {40960,82176,82432,82688,82944,83200,83456,83712,
                            100352,116800,116864,116928,116992,117056,117120,117184,
                            127488,127552, 127616};
        for (int e = threadIdx.x; e < 2689; e += 256) {
            int rem = e, t = 0;
            while (rem >= SZ[t]) { rem -= SZ[t]; ++t; }
            const float* pf = (const float*)s.sp[t];
            const ushort* pu = (const ushort*)s.sp[t];
            params[OF[t] + rem] = f32 ? f2b(pf[rem]) : pu[rem];
        }
    }
}

// ---------------- CSR build (reads raw edge_index, flag-dependent stride) ----------------
__global__ void hist_k(const int* __restrict__ ei, const int* __restrict__ flags,
                       int* __restrict__ deg) {
    int e = blockIdx.x * 256 + threadIdx.x;
    if (e >= EP_EDGES) return;
    int dst;
    if (e < E_EDGES) {
        int idx = E_EDGES + e;
        dst = flags[1] ? ei[2 * idx] : ei[idx];
    } else dst = e - E_EDGES;
    atomicAdd(&deg[dst], 1);
}

__global__ __launch_bounds__(1024) void scan1_k(const int* __restrict__ deg,
                                                int* __restrict__ exc,
                                                int* __restrict__ bsum) {
    __shared__ int s[1024];
    int i = blockIdx.x * 1024 + threadIdx.x;
    int v = (i < N_NODES) ? deg[i] : 0;
    s[threadIdx.x] = v;
    __syncthreads();
    for (int off = 1; off < 1024; off <<= 1) {
        int t = (threadIdx.x >= off) ? s[threadIdx.x - off] : 0;
        __syncthreads();
        s[threadIdx.x] += t;
        __syncthreads();
    }
    if (i < N_NODES) exc[i] = s[threadIdx.x] - v;
    if (threadIdx.x == 1023) bsum[blockIdx.x] = s[1023];
}

__global__ void scan2_k(int* __restrict__ bsum, int nb) {
    int lane = threadIdx.x;  // single wave of 64
    int v = (lane < nb) ? bsum[lane] : 0;
    int orig = v;
    #pragma unroll
    for (int d = 1; d < 64; d <<= 1) {
        int t = __shfl_up(v, d);
        if (lane >= d) v += t;
    }
    if (lane < nb) bsum[lane] = v - orig;
}

__global__ void scan3_k(int* __restrict__ row_ptr, const int* __restrict__ bsum,
                        int* __restrict__ rowcur) {
    int i = blockIdx.x * 256 + threadIdx.x;
    if (i >= N_NODES) return;
    int rp = row_ptr[i] + bsum[i >> 10];
    row_ptr[i] = rp;
    rowcur[i] = rp;
    if (i == 0) row_ptr[N_NODES] = EP_EDGES;
}

__global__ void scatter_k(const int* __restrict__ ei, const int* __restrict__ flags,
                          int* __restrict__ rowcur, int* __restrict__ col) {
    int e = blockIdx.x * 256 + threadIdx.x;
    if (e >= EP_EDGES) return;
    int src, dst;
    if (e < E_EDGES) {
        if (flags[1]) { src = ei[2 * e]; dst = ei[2 * (E_EDGES + e)]; }
        else          { src = ei[e];     dst = ei[E_EDGES + e]; }
    } else { src = e - E_EDGES; dst = src; }
    int pos = atomicAdd(&rowcur[dst], 1);
    col[pos] = src;
}

// ---------------- fused layer-1 MFMA GEMM, split-N, 2 row-tiles/wave ----------------
__global__ __launch_bounds__(256) void gemm3_k(const ushort* __restrict__ A,
                                               const ushort* __restrict__ B1,
                                               const ushort* __restrict__ B2,
                                               const ushort* __restrict__ B3,
                                               const ushort* __restrict__ bi1,
                                               const ushort* __restrict__ bi2,
                                               const ushort* __restrict__ bi3,
                                               ushort* __restrict__ o1,
                                               ushort* __restrict__ o2,
                                               ushort* __restrict__ o3,
                                               int M) {
    const int wave = threadIdx.x >> 6;
    const int lane = threadIdx.x & 63;
    const int ch = blockIdx.y;
    const int row0 = blockIdx.x * 128 + wave * 32;
    if (row0 >= M) return;
    int ar0 = row0 + (lane & 15);      if (ar0 >= M) ar0 = M - 1;
    int ar1 = row0 + 16 + (lane & 15); if (ar1 >= M) ar1 = M - 1;
    const ushort* ap0 = A + (size_t)ar0 * IN_DIM + (lane >> 4) * 8;
    const ushort* ap1 = A + (size_t)ar1 * IN_DIM + (lane >> 4) * 8;
    bf16x8 af0[5], af1[5];
    #pragma unroll
    for (int kb = 0; kb < 5; ++kb) {
        af0[kb] = *(const bf16x8*)(ap0 + kb * 32);
        af1[kb] = *(const bf16x8*)(ap1 + kb * 32);
    }
    const bf16x8* b1 = (const bf16x8*)B1;
    const bf16x8* b2 = (const bf16x8*)B2;
    const bf16x8* b3 = (const bf16x8*)B3;
    f32x4 aL[2][8] = {}, aR[2][8] = {}, aS[2][2] = {};
    #pragma unroll
    for (int kb = 0; kb < 5; ++kb) {
        #pragma unroll
        for (int j = 0; j < 8; ++j) {
            bf16x8 b = b1[(kb * 16 + ch * 8 + j) * 64 + lane];
            aL[0][j] = __builtin_amdgcn_mfma_f32_16x16x32_bf16(af0[kb], b, aL[0][j], 0, 0, 0);
            aL[1][j] = __builtin_amdgcn_mfma_f32_16x16x32_bf16(af1[kb], b, aL[1][j], 0, 0, 0);
        }
        #pragma unroll
        for (int j = 0; j < 8; ++j) {
            bf16x8 b = b2[(kb * 16 + ch * 8 + j) * 64 + lane];
            aR[0][j] = __builtin_amdgcn_mfma_f32_16x16x32_bf16(af0[kb], b, aR[0][j], 0, 0, 0);
            aR[1][j] = __builtin_amdgcn_mfma_f32_16x16x32_bf16(af1[kb], b, aR[1][j], 0, 0, 0);
        }
        #pragma unroll
        for (int j = 0; j < 2; ++j) {
            bf16x8 b = b3[(kb * 4 + ch * 2 + j) * 64 + lane];
            aS[0][j] = __builtin_amdgcn_mfma_f32_16x16x32_bf16(af0[kb], b, aS[0][j], 0, 0, 0);
            aS[1][j] = __builtin_amdgcn_mfma_f32_16x16x32_bf16(af1[kb], b, aS[1][j], 0, 0, 0);
        }
    }
    const int cn = lane & 15, cq = lane >> 4;
    #pragma unroll
    for (int rt = 0; rt < 2; ++rt) {
        #pragma unroll
        for (int j = 0; j < 8; ++j) {
            int colc = (ch * 8 + j) * 16 + cn;
            float bbL = b2f(bi1[colc]);
            float bbR = b2f(bi2[colc]);
            #pragma unroll
            for (int r = 0; r < 4; ++r) {
                int grow = row0 + rt * 16 + cq * 4 + r;
                if (grow < M) {
                    o1[(size_t)grow * C1 + colc] = f2b(aL[rt][j][r] + bbL);
                    o2[(size_t)grow * C1 + colc] = f2b(aR[rt][j][r] + bbR);
                }
            }
        }
        #pragma unroll
        for (int j = 0; j < 2; ++j) {
            int colc = (ch * 2 + j) * 16 + cn;
            float bb = b2f(bi3[colc]);
            #pragma unroll
            for (int r = 0; r < 4; ++r) {
                int grow = row0 + rt * 16 + cq * 4 + r;
                if (grow < M)
                    o3[(size_t)grow * HID + colc] = f2b(aS[rt][j][r] + bb);
            }
        }
    }
}

// ---------------- fused layer-2 MFMA GEMM: xl2(64) + xr2(64), K=256 ----------------
__global__ __launch_bounds__(256) void gemm2_k(const ushort* __restrict__ A,
                                               const ushort* __restrict__ B1,
                                               const ushort* __restrict__ B2,
                                               const ushort* __restrict__ bi1,
                                               const ushort* __restrict__ bi2,
                                               ushort* __restrict__ o1,
                                               ushort* __restrict__ o2,
                                               int M) {
    const int wave = threadIdx.x >> 6;
    const int lane = threadIdx.x & 63;
    const int row0 = blockIdx.x * 64 + wave * 16;
    if (row0 >= M) return;
    int arow = row0 + (lane & 15);
    if (arow >= M) arow = M - 1;
    const ushort* aptr = A + (size_t)arow * C1 + (lane >> 4) * 8;
    const bf16x8* b1 = (const bf16x8*)B1;
    const bf16x8* b2 = (const bf16x8*)B2;
    f32x4 aL[4] = {}, aR[4] = {};
    #pragma unroll
    for (int kb = 0; kb < 8; ++kb) {
        bf16x8 af = *(const bf16x8*)(aptr + kb * 32);
        #pragma unroll
        for (int t = 0; t < 4; ++t)
            aL[t] = __builtin_amdgcn_mfma_f32_16x16x32_bf16(af, b1[(kb * 4 + t) * 64 + lane], aL[t], 0, 0, 0);
        #pragma unroll
        for (int t = 0; t < 4; ++t)
            aR[t] = __builtin_amdgcn_mfma_f32_16x16x32_bf16(af, b2[(kb * 4 + t) * 64 + lane], aR[t], 0, 0, 0);
    }
    const int cn = lane & 15, cq = lane >> 4;
    #pragma unroll
    for (int t = 0; t < 4; ++t) {
        float bbL = b2f(bi1[t * 16 + cn]);
        float bbR = b2f(bi2[t * 16 + cn]);
        #pragma unroll
        for (int r = 0; r < 4; ++r) {
            int grow = row0 + cq * 4 + r;
            if (grow < M) {
                o1[(size_t)grow * HID + t * 16 + cn] = f2b(aL[t][r] + bbL);
                o2[(size_t)grow * HID + t * 16 + cn] = f2b(aR[t][r] + bbR);
            }
        }
    }
}

// ---------------- conv1: pk-f32 math, 8 edges/trip, 16 lanes/edge, 4 ch/lane ----------------
// logit = (0.6att)·t + (0.4att)·|t|  (leaky-relu decomposition, no mul/max chain)
__global__ __launch_bounds__(256) void conv1_k(const ushort* __restrict__ xl,
                                               const ushort* __restrict__ xr,
                                               const int* __restrict__ row_ptr,
                                               const int* __restrict__ col,
                                               const ushort* __restrict__ att,
                                               const ushort* __restrict__ bias1,
                                               const ushort* __restrict__ g1,
                                               const ushort* __restrict__ b1,
                                               const ushort* __restrict__ m1,
                                               const ushort* __restrict__ v1,
                                               ushort* __restrict__ h1out) {
    const int n = blockIdx.x;
    const int h = threadIdx.x >> 6;          // wave = head
    const int lane = threadIdx.x & 63;
    const int grp = lane >> 4;               // edge slot 0..3
    const int m = lane & 15;                 // channel quad
    const uint cpi = h * 16 + m;             // uint2 index within 64-uint2 row
    const uint2* xl2v = (const uint2*)xl;
    const uint2 xru = ((const uint2*)xr)[(size_t)n * 64 + cpi];
    const f32x2 xr01 = unpk(xru.x), xr23 = unpk(xru.y);
    const uint2 atu = ((const uint2*)att)[cpi];
    const f32x2 at01 = unpk(atu.x), at23 = unpk(atu.y);
    const f32x2 a06_01 = at01 * 0.6f, a06_23 = at23 * 0.6f;
    const f32x2 a04_01 = at01 * 0.4f, a04_23 = at23 * 0.4f;
    const int e0 = row_ptr[n], e1 = row_ptr[n + 1];
    f32x2 acc01 = {0.f, 0.f}, acc23 = {0.f, 0.f};
    float den = 0.f;
    const int jA = e0 + grp, jB = e0 + 4 + grp;
    uint sA = (uint)col[jA < e1 ? jA : e1 - 1];
    uint sB = (uint)col[jB < e1 ? jB : e1 - 1];
    for (int i = e0; i < e1; i += 8) {
        const uint2 xuA = xl2v[(sA << 6) + cpi];
        const uint2 xuB = xl2v[(sB << 6) + cpi];
        const int jC = i + 8 + grp, jD = i + 12 + grp;
        const uint sC = (uint)col[jC < e1 ? jC : e1 - 1];
        const uint sD = (uint)col[jD < e1 ? jD : e1 - 1];
        const bool vA = (i + grp) < e1, vB = (i + 4 + grp) < e1;
        // edge A
        const f32x2 xa01 = unpk(xuA.x), xa23 = unpk(xuA.y);
        f32x2 tA01 = xa01 + xr01, tA23 = xa23 + xr23;            // v_pk_add
        f32x2 uA01 = __builtin_elementwise_abs(tA01);
        f32x2 uA23 = __builtin_elementwise_abs(tA23);
        f32x2 ppA = tA01 * a06_01;                               // v_pk_mul
        ppA = __builtin_elementwise_fma(uA01, a04_01, ppA);      // v_pk_fma
        ppA = __builtin_elementwise_fma(tA23, a06_23, ppA);
        ppA = __builtin_elementwise_fma(uA23, a04_23, ppA);
        float pA = row16_sum(ppA.x + ppA.y);
        const float wA = vA ? __expf(fminf(pA, 60.f)) : 0.f;
        // edge B
        const f32x2 xb01 = unpk(xuB.x), xb23 = unpk(xuB.y);
        f32x2 tB01 = xb01 + xr01, tB23 = xb23 + xr23;
        f32x2 uB01 = __builtin_elementwise_abs(tB01);
        f32x2 uB23 = __builtin_elementwise_abs(tB23);
        f32x2 ppB = tB01 * a06_01;
        ppB = __builtin_elementwise_fma(uB01, a04_01, ppB);
        ppB = __builtin_elementwise_fma(tB23, a06_23, ppB);
        ppB = __builtin_elementwise_fma(uB23, a04_23, ppB);
        float pB = row16_sum(ppB.x + ppB.y);
        const float wB = vB ? __expf(fminf(pB, 60.f)) : 0.f;
        // accumulate (packed)
        const f32x2 wwA = {wA, wA}, wwB = {wB, wB};
        acc01 = __builtin_elementwise_fma(wwA, xa01, acc01);
        acc23 = __builtin_elementwise_fma(wwA, xa23, acc23);
        acc01 = __builtin_elementwise_fma(wwB, xb01, acc01);
        acc23 = __builtin_elementwise_fma(wwB, xb23, acc23);
        den += wA + wB;
        sA = sC; sB = sD;
    }
    float a0 = acc01.x, a1 = acc01.y, a2 = acc23.x, a3 = acc23.y;
    a0 += __shfl_xor(a0, 16); a0 += __shfl_xor(a0, 32);
    a1 += __shfl_xor(a1, 16); a1 += __shfl_xor(a1, 32);
    a2 += __shfl_xor(a2, 16); a2 += __shfl_xor(a2, 32);
    a3 += __shfl_xor(a3, 16); a3 += __shfl_xor(a3, 32);
    den += __shfl_xor(den, 16); den += __shfl_xor(den, 32);
    if (lane < 16) {
        const float inv = 1.f / den;
        const uint2 biu = ((const uint2*)bias1)[cpi];
        const uint2 gu  = ((const uint2*)g1)[cpi];
        const uint2 bu  = ((const uint2*)b1)[cpi];
        const uint2 mu  = ((const uint2*)m1)[cpi];
        const uint2 vu  = ((const uint2*)v1)[cpi];
        float o0 = fmaf(a0, inv, lo16(biu.x));
        float o1 = fmaf(a1, inv, hi16(biu.x));
        float o2 = fmaf(a2, inv, lo16(biu.y));
        float o3 = fmaf(a3, inv, hi16(biu.y));
        float s0 = lo16(gu.x) * rsqrtf(lo16(vu.x) + BN_EPS);
        float s1 = hi16(gu.x) * rsqrtf(hi16(vu.x) + BN_EPS);
        float s2 = lo16(gu.y) * rsqrtf(lo16(vu.y) + BN_EPS);
        float s3 = hi16(gu.y) * rsqrtf(hi16(vu.y) + BN_EPS);
        float h0 = fmaxf((o0 - lo16(mu.x)) * s0 + lo16(bu.x), 0.f);
        float h1v = fmaxf((o1 - hi16(mu.x)) * s1 + hi16(bu.x), 0.f);
        float h2 = fmaxf((o2 - lo16(mu.y)) * s2 + lo16(bu.y), 0.f);
        float h3 = fmaxf((o3 - hi16(mu.y)) * s3 + hi16(bu.y), 0.f);
        uint2 ou;
        ou.x = (uint)f2b(h0) | ((uint)f2b(h1v) << 16);
        ou.y = (uint)f2b(h2) | ((uint)f2b(h3) << 16);
        ((uint2*)h1out)[(size_t)n * 64 + cpi] = ou;
    }
}

// ---------------- conv2 + BN2 + relu + skip + output linear (pk-f32) ----------------
__global__ __launch_bounds__(256) void conv2_k(const ushort* __restrict__ xl,
                                               const ushort* __restrict__ xr,
                                               const ushort* __restrict__ xskip,
                                               const int* __restrict__ row_ptr,
                                               const int* __restrict__ col,
                                               const ushort* __restrict__ att2,
                                               const ushort* __restrict__ bias2,
                                               const ushort* __restrict__ g2,
                                               const ushort* __restrict__ bb2,
                                               const ushort* __restrict__ m2,
                                               const ushort* __restrict__ v2,
                                               const ushort* __restrict__ Wo,
                                               const ushort* __restrict__ bo,
                                               void* __restrict__ out,
                                               const int* __restrict__ flags) {
    const int n = blockIdx.x * 4 + (threadIdx.x >> 6);
    if (n >= N_NODES) return;
    const int lane = threadIdx.x & 63;
    const int grp = lane >> 4;
    const uint m = lane & 15;                // uint2 index within 16-uint2 row
    const uint2* xl2v = (const uint2*)xl;
    const uint2 xru = ((const uint2*)xr)[(size_t)n * 16 + m];
    const f32x2 xr01 = unpk(xru.x), xr23 = unpk(xru.y);
    const uint2 atu = ((const uint2*)att2)[m];
    const f32x2 at01 = unpk(atu.x), at23 = unpk(atu.y);
    const f32x2 a06_01 = at01 * 0.6f, a06_23 = at23 * 0.6f;
    const f32x2 a04_01 = at01 * 0.4f, a04_23 = at23 * 0.4f;
    const int e0 = row_ptr[n], e1 = row_ptr[n + 1];
    f32x2 acc01 = {0.f, 0.f}, acc23 = {0.f, 0.f};
    float den = 0.f;
    const int jA = e0 + grp, jB = e0 + 4 + grp;
    uint sA = (uint)col[jA < e1 ? jA : e1 - 1];
    uint sB = (uint)col[jB < e1 ? jB : e1 - 1];
    for (int i = e0; i < e1; i += 8) {
        const uint2 xuA = xl2v[(sA << 4) + m];
        const uint2 xuB = xl2v[(sB << 4) + m];
        const int jC = i + 8 + grp, jD = i + 12 + grp;
        const uint sC = (uint)col[jC < e1 ? jC : e1 - 1];
        const uint sD = (uint)col[jD < e1 ? jD : e1 - 1];
        const bool vA = (i + grp) < e1, vB = (i + 4 + grp) < e1;
        const f32x2 xa01 = unpk(xuA.x), xa23 = unpk(xuA.y);
        f32x2 tA01 = xa01 + xr01, tA23 = xa23 + xr23;
        f32x2 uA01 = __builtin_elementwise_abs(tA01);
        f32x2 uA23 = __builtin_elementwise_abs(tA23);
        f32x2 ppA = tA01 * a06_01;
        ppA = __builtin_elementwise_fma(uA01, a04_01, ppA);
        ppA = __builtin_elementwise_fma(tA23, a06_23, ppA);
        ppA = __builtin_elementwise_fma(uA23, a04_23, ppA);
        float pA = row16_sum(ppA.x + ppA.y);
        const float wA = vA ? __expf(fminf(pA, 60.f)) : 0.f;
        const f32x2 xb01 = unpk(xuB.x), xb23 = unpk(xuB.y);
        f32x2 tB01 = xb01 + xr01, tB23 = xb23 + xr23;
        f32x2 uB01 = __builtin_elementwise_abs(tB01);
        f32x2 uB23 = __builtin_elementwise_abs(tB23);
        f32x2 ppB = tB01 * a06_01;
        ppB = __builtin_elementwise_fma(uB01, a04_01, ppB);
        ppB = __builtin_elementwise_fma(tB23, a06_23, ppB);
        ppB = __builtin_elementwise_fma(uB23, a04_23, ppB);
        float pB = row16_sum(ppB.x + ppB.y);
        const float wB = vB ? __expf(fminf(pB, 60.f)) : 0.f;
        const f32x2 wwA = {wA, wA}, wwB = {wB, wB};
        acc01 = __builtin_elementwise_fma(wwA, xa01, acc01);
        acc23 = __builtin_elementwise_fma(wwA, xa23, acc23);
        acc01 = __builtin_elementwise_fma(wwB, xb01, acc01);
        acc23 = __builtin_elementwise_fma(wwB, xb23, acc23);
        den += wA + wB;
        sA = sC; sB = sD;
    }
    float a0 = acc01.x, a1 = acc01.y, a2 = acc23.x, a3 = acc23.y;
    a0 += __shfl_xor(a0, 16); a0 += __shfl_xor(a0, 32);
    a1 += __shfl_xor(a1, 16); a1 += __shfl_xor(a1, 32);
    a2 += __shfl_xor(a2, 16); a2 += __shfl_xor(a2, 32);
    a3 += __shfl_xor(a3, 16); a3 += __shfl_xor(a3, 32);
    den += __shfl_xor(den, 16); den += __shfl_xor(den, 32);
    if (lane < 16) {
        const float inv = 1.f / den;
        const uint2 biu = ((const uint2*)bias2)[m];
        const uint2 gu  = ((const uint2*)g2)[m];
        const uint2 bu  = ((const uint2*)bb2)[m];
        const uint2 mu  = ((const uint2*)m2)[m];
        const uint2 vu  = ((const uint2*)v2)[m];
        const uint2 sku = ((const uint2*)xskip)[(size_t)n * 16 + m];
        const uint2 wou = ((const uint2*)Wo)[m];
        float o0 = fmaf(a0, inv, lo16(biu.x));
        float o1 = fmaf(a1, inv, hi16(biu.x));
        float o2 = fmaf(a2, inv, lo16(biu.y));
        float o3 = fmaf(a3, inv, hi16(biu.y));
        float s0 = lo16(gu.x) * rsqrtf(lo16(vu.x) + BN_EPS);
        float s1 = hi16(gu.x) * rsqrtf(hi16(vu.x) + BN_EPS);
        float s2 = lo16(gu.y) * rsqrtf(lo16(vu.y) + BN_EPS);
        float s3 = hi16(gu.y) * rsqrtf(hi16(vu.y) + BN_EPS);
        float h0 = fmaxf((o0 - lo16(mu.x)) * s0 + lo16(bu.x), 0.f) + lo16(sku.x);
        float h1v = fmaxf((o1 - hi16(mu.x)) * s1 + hi16(bu.x), 0.f) + hi16(sku.x);
        float h2 = fmaxf((o2 - lo16(mu.y)) * s2 + lo16(bu.y), 0.f) + lo16(sku.y);
        float h3 = fmaxf((o3 - hi16(mu.y)) * s3 + hi16(bu.y), 0.f) + hi16(sku.y);
        float d = fmaf(h0, lo16(wou.x), fmaf(h1v, hi16(wou.x),
                  fmaf(h2, lo16(wou.y), h3 * hi16(wou.y))));
        d = row16_sum(d);
        if (m == 0) {
            float r = d + b2f(bo[0]);
            if (flags[0]) ((float*)out)[n] = r;
            else          ((ushort*)out)[n] = f2b(r);
        }
    }
}

extern "C" void kernel_launch(void* const* d_in, const int* in_sizes, int n_in,
                              void* d_out, int out_size, void* d_ws, size_t ws_size,
                              hipStream_t stream) {
    char* ws = (char*)d_ws;
    size_t off = 0;
    auto alloc = [&](size_t bytes) -> void* {
        void* p = ws + off;
        off += (bytes + 255) & ~(size_t)255;
        return p;
    };
    int*    flags   = (int*)alloc(256);
    ushort* params  = (ushort*)alloc((size_t)127617 * 2);
    ushort* x_c     = (ushort*)alloc((size_t)N_NODES * IN_DIM * 2);
    int*    row_ptr = (int*)alloc((size_t)(N_NODES + 1) * 4);
    int*    rowcur  = (int*)alloc((size_t)N_NODES * 4);
    int*    deg     = (int*)alloc((size_t)N_NODES * 4);
    int*    colbuf  = (int*)alloc((size_t)EP_EDGES * 4);
    int*    bsum    = (int*)alloc(64 * 4);
    ushort* xl1     = (ushort*)alloc((size_t)N_NODES * C1 * 2);
    ushort* xr1     = (ushort*)alloc((size_t)N_NODES * C1 * 2);
    ushort* xskip   = (ushort*)alloc((size_t)N_NODES * HID * 2);
    ushort* h1      = (ushort*)alloc((size_t)N_NODES * C1 * 2);
    ushort* xl2     = (ushort*)alloc((size_t)N_NODES * HID * 2);
    ushort* xr2     = (ushort*)alloc((size_t)N_NODES * HID * 2);
    ushort* swzWl1  = (ushort*)alloc((size_t)IN_DIM * C1 * 2);
    ushort* swzWr1  = (ushort*)alloc((size_t)IN_DIM * C1 * 2);
    ushort* swzWs   = (ushort*)alloc((size_t)IN_DIM * HID * 2);
    ushort* swzWl2  = (ushort*)alloc((size_t)C1 * HID * 2);
    ushort* swzWr2  = (ushort*)alloc((size_t)C1 * HID * 2);

    ushort* bl1c   = params + 40960;
    ushort* br1c   = params + 82176;
    ushort* att1c  = params + 82432;
    ushort* bias1c = params + 82688;
    ushort* g1c    = params + 82944;
    ushort* b1c    = params + 83200;
    ushort* m1c    = params + 83456;
    ushort* v1c    = params + 83712;
    ushort* bl2c   = params + 100352;
    ushort* br2c   = params + 116800;
    ushort* att2c  = params + 116864;
    ushort* bias2c = params + 116928;
    ushort* g2c    = params + 116992;
    ushort* b2c    = params + 117056;
    ushort* m2c    = params + 117120;
    ushort* v2c    = params + 117184;
    ushort* bsc    = params + 127488;
    ushort* Woc    = params + 127552;
    ushort* boc    = params + 127616;

    // ---- detect dtypes, canonicalize x, swizzle weights + small params ----
    detect_k<<<1, 64, 0, stream>>>((const ushort*)d_in[0], (const int*)d_in[1], flags);
    cvt_x_k<<<(N_NODES * IN_DIM + 255) / 256, 256, 0, stream>>>(d_in[0], x_c, flags, deg);

    SW2 sw;
    sw.W[0] = d_in[2];  sw.D[0] = swzWl1; sw.NT[0] = 16; sw.base[0] = 0;      // Wl1
    sw.W[1] = d_in[4];  sw.D[1] = swzWr1; sw.NT[1] = 16; sw.base[1] = 5120;   // Wr1
    sw.W[2] = d_in[22]; sw.D[2] = swzWs;  sw.NT[2] = 4;  sw.base[2] = 10240;  // Ws
    sw.W[3] = d_in[12]; sw.D[3] = swzWl2; sw.NT[3] = 4;  sw.base[3] = 11520;  // Wl2
    sw.W[4] = d_in[14]; sw.D[4] = swzWr2; sw.NT[4] = 4;  sw.base[4] = 13568;  // Wr2
    const int spidx[19] = {3,5,6,7,8,9,10,11, 13,15,16,17,18,19,20,21, 23,24, 25};
    for (int i = 0; i < 19; ++i) sw.sp[i] = d_in[spidx[i]];
    swzp_k<<<62, 256, 0, stream>>>(sw, params, flags);

    const int NB_N = (N_NODES + 255) / 256;        // 196
    const int NB_E = (EP_EDGES + 255) / 256;       // 3321
    const int NB_S = (N_NODES + 1023) / 1024;      // 49

    // ---- CSR build (reads raw edge_index) ----
    const int* ei_raw = (const int*)d_in[1];
    hist_k<<<NB_E, 256, 0, stream>>>(ei_raw, flags, deg);
    scan1_k<<<NB_S, 1024, 0, stream>>>(deg, row_ptr, bsum);
    scan2_k<<<1, 64, 0, stream>>>(bsum, NB_S);
    scan3_k<<<NB_N, 256, 0, stream>>>(row_ptr, bsum, rowcur);
    scatter_k<<<NB_E, 256, 0, stream>>>(ei_raw, flags, rowcur, colbuf);

    // ---- layer-1 linear transforms (+ skip), fused MFMA (split-N, 2 row-tiles/wave) ----
    gemm3_k<<<dim3((N_NODES + 127) / 128, 2), 256, 0, stream>>>(
        x_c, swzWl1, swzWr1, swzWs, bl1c, br1c, bsc, xl1, xr1, xskip, N_NODES);

    // ---- conv1 edge aggregation + BN1 + relu ----
    conv1_k<<<N_NODES, 256, 0, stream>>>(xl1, xr1, row_ptr, colbuf, att1c, bias1c,
                                         g1c, b1c, m1c, v1c, h1);

    // ---- layer-2 linear transforms, fused MFMA ----
    gemm2_k<<<(N_NODES + 63) / 64, 256, 0, stream>>>(h1, swzWl2, swzWr2, bl2c, br2c,
                                                     xl2, xr2, N_NODES);

    // ---- conv2 + BN2 + relu + skip + output linear ----
    conv2_k<<<(N_NODES + 3) / 4, 256, 0, stream>>>(xl2, xr2, xskip, row_ptr, colbuf,
                                                   att2c, bias2c, g2c, b2c, m2c, v2c,
                                                   Woc, boc, d_out, flags);
}

// Round 9
// 424.688 us; speedup vs baseline: 1.0280x; 1.0280x over previous
//
#include <hip/hip_runtime.h>
#include <hip/hip_bf16.h>

#define N_NODES 50000
#define E_EDGES 800000
#define EP_EDGES 850000   // E + N self loops
#define IN_DIM 160
#define HEADS 4
#define HID 64
#define C1 256            // HEADS*HID
#define NEG_SLOPE 0.2f
#define BN_EPS 1e-5f

typedef __attribute__((ext_vector_type(8))) short bf16x8;
typedef __attribute__((ext_vector_type(4))) float f32x4;

__device__ __forceinline__ float b2f(ushort u) {
    return __uint_as_float(((unsigned)u) << 16);
}
__device__ __forceinline__ ushort f2b(float f) {
    __hip_bfloat16 h = __float2bfloat16(f);
    return *reinterpret_cast<ushort*>(&h);
}
__device__ __forceinline__ float lo16(uint u) { return __uint_as_float(u << 16); }
__device__ __forceinline__ float hi16(uint u) { return __uint_as_float(u & 0xffff0000u); }

// DPP-based add of a permuted copy: pure VALU pipe
template<int CTRL>
__device__ __forceinline__ float dpp_add(float p) {
    int t = __builtin_amdgcn_update_dpp(0, __float_as_int(p), CTRL, 0xf, 0xf, true);
    return p + __int_as_float(t);
}
// sum over each 16-lane row; all 16 lanes get the row total
__device__ __forceinline__ float row16_sum(float p) {
    p = dpp_add<0xB1>(p);    // quad_perm xor1
    p = dpp_add<0x4E>(p);    // quad_perm xor2
    p = dpp_add<0x124>(p);   // row_ror:4
    p = dpp_add<0x128>(p);   // row_ror:8
    return p;
}

// ---------------- runtime dtype detection ----------------
// flags[0]: 1 if float tensors are fp32 on device; flags[1]: 1 if edges int64
__global__ void detect_k(const ushort* __restrict__ xraw,
                         const int* __restrict__ eraw,
                         int* __restrict__ flags) {
    int lane = threadIdx.x;  // 64 threads
    int good = 0, nz = 0;
    for (int i = lane; i < 256; i += 64) {
        float a = fabsf(b2f(xraw[2 * i]));
        good += (a > 1e-6f && a < 1e6f) ? 1 : 0;
        nz += (eraw[2 * i + 1] != 0) ? 1 : 0;
    }
    #pragma unroll
    for (int off = 32; off > 0; off >>= 1) {
        good += __shfl_xor(good, off);
        nz += __shfl_xor(nz, off);
    }
    if (lane == 0) {
        flags[0] = (good < 192) ? 1 : 0;
        flags[1] = (nz == 0) ? 1 : 0;
    }
}

// ---------------- canonicalize x -> bf16 (also zeroes deg) ----------------
__global__ void cvt_x_k(const void* __restrict__ src, ushort* __restrict__ dst,
                        const int* __restrict__ flags, int* __restrict__ deg) {
    int i = blockIdx.x * 256 + threadIdx.x;
    if (i < N_NODES) deg[i] = 0;
    if (i >= N_NODES * IN_DIM) return;
    dst[i] = flags[0] ? f2b(((const float*)src)[i]) : ((const ushort*)src)[i];
}

// ---------------- merged: weight swizzle (raw->MFMA frag order) + small-param canonicalize ----------------
struct SW2 {
    const void* W[5];    // raw Wl1, Wr1, Ws, Wl2, Wr2
    ushort* D[5];
    int NT[5];
    int base[5];
    const void* sp[19];  // raw small tensors
};

__global__ void swzp_k(SW2 s, ushort* __restrict__ params,
                       const int* __restrict__ flags) {
    const bool f32 = flags[0] != 0;
    if (blockIdx.x < 61) {
        int idx = blockIdx.x * 256 + threadIdx.x;   // < 15616
        int seg = 0;
        #pragma unroll
        for (int k = 1; k < 5; ++k) seg += (idx >= s.base[k]) ? 1 : 0;
        int li = idx - s.base[seg];
        int NT = s.NT[seg];
        int N = NT << 4;
        int lane = li & 63;
        int ft = li >> 6;
        int kb = ft / NT, t = ft - kb * NT;
        int q = lane >> 4, m = lane & 15;
        const float* pf = (const float*)s.W[seg];
        const ushort* pu = (const ushort*)s.W[seg];
        ushort* d = s.D[seg] + (size_t)li * 8;
        #pragma unroll
        for (int j = 0; j < 8; ++j) {
            size_t src = (size_t)(kb * 32 + q * 8 + j) * N + t * 16 + m;
            d[j] = f32 ? f2b(pf[src]) : pu[src];
        }
    } else {
        const int SZ[19] = {256,256,256,256,256,256,256,256,
                            64,64,64,64,64,64,64,64,64,64, 1};
        const int OF[19] = {40960,82176,82432,82688,82944,83200,83456,83712,
                            100352,116800,116864,116928,116992,117056,117120,117184,
                            127488,127552, 127616};
        for (int e = threadIdx.x; e < 2689; e += 256) {
            int rem = e, t = 0;
            while (rem >= SZ[t]) { rem -= SZ[t]; ++t; }
            const float* pf = (const float*)s.sp[t];
            const ushort* pu = (const ushort*)s.sp[t];
            params[OF[t] + rem] = f32 ? f2b(pf[rem]) : pu[rem];
        }
    }
}

// ---------------- CSR build (reads raw edge_index, flag-dependent stride) ----------------
__global__ void hist_k(const int* __restrict__ ei, const int* __restrict__ flags,
                       int* __restrict__ deg) {
    int e = blockIdx.x * 256 + threadIdx.x;
    if (e >= EP_EDGES) return;
    int dst;
    if (e < E_EDGES) {
        int idx = E_EDGES + e;
        dst = flags[1] ? ei[2 * idx] : ei[idx];
    } else dst = e - E_EDGES;
    atomicAdd(&deg[dst], 1);
}

__global__ __launch_bounds__(1024) void scan1_k(const int* __restrict__ deg,
                                                int* __restrict__ exc,
                                                int* __restrict__ bsum) {
    __shared__ int s[1024];
    int i = blockIdx.x * 1024 + threadIdx.x;
    int v = (i < N_NODES) ? deg[i] : 0;
    s[threadIdx.x] = v;
    __syncthreads();
    for (int off = 1; off < 1024; off <<= 1) {
        int t = (threadIdx.x >= off) ? s[threadIdx.x - off] : 0;
        __syncthreads();
        s[threadIdx.x] += t;
        __syncthreads();
    }
    if (i < N_NODES) exc[i] = s[threadIdx.x] - v;
    if (threadIdx.x == 1023) bsum[blockIdx.x] = s[1023];
}

__global__ void scan2_k(int* __restrict__ bsum, int nb) {
    int lane = threadIdx.x;  // single wave of 64
    int v = (lane < nb) ? bsum[lane] : 0;
    int orig = v;
    #pragma unroll
    for (int d = 1; d < 64; d <<= 1) {
        int t = __shfl_up(v, d);
        if (lane >= d) v += t;
    }
    if (lane < nb) bsum[lane] = v - orig;
}

__global__ void scan3_k(int* __restrict__ row_ptr, const int* __restrict__ bsum,
                        int* __restrict__ rowcur) {
    int i = blockIdx.x * 256 + threadIdx.x;
    if (i >= N_NODES) return;
    int rp = row_ptr[i] + bsum[i >> 10];
    row_ptr[i] = rp;
    rowcur[i] = rp;
    if (i == 0) row_ptr[N_NODES] = EP_EDGES;
}

__global__ void scatter_k(const int* __restrict__ ei, const int* __restrict__ flags,
                          int* __restrict__ rowcur, int* __restrict__ col) {
    int e = blockIdx.x * 256 + threadIdx.x;
    if (e >= EP_EDGES) return;
    int src, dst;
    if (e < E_EDGES) {
        if (flags[1]) { src = ei[2 * e]; dst = ei[2 * (E_EDGES + e)]; }
        else          { src = ei[e];     dst = ei[E_EDGES + e]; }
    } else { src = e - E_EDGES; dst = src; }
    int pos = atomicAdd(&rowcur[dst], 1);
    col[pos] = src;
}

// ---------------- fused layer-1 MFMA GEMM, split-N, 2 row-tiles/wave ----------------
__global__ __launch_bounds__(256) void gemm3_k(const ushort* __restrict__ A,
                                               const ushort* __restrict__ B1,
                                               const ushort* __restrict__ B2,
                                               const ushort* __restrict__ B3,
                                               const ushort* __restrict__ bi1,
                                               const ushort* __restrict__ bi2,
                                               const ushort* __restrict__ bi3,
                                               ushort* __restrict__ o1,
                                               ushort* __restrict__ o2,
                                               ushort* __restrict__ o3,
                                               int M) {
    const int wave = threadIdx.x >> 6;
    const int lane = threadIdx.x & 63;
    const int ch = blockIdx.y;
    const int row0 = blockIdx.x * 128 + wave * 32;
    if (row0 >= M) return;
    int ar0 = row0 + (lane & 15);      if (ar0 >= M) ar0 = M - 1;
    int ar1 = row0 + 16 + (lane & 15); if (ar1 >= M) ar1 = M - 1;
    const ushort* ap0 = A + (size_t)ar0 * IN_DIM + (lane >> 4) * 8;
    const ushort* ap1 = A + (size_t)ar1 * IN_DIM + (lane >> 4) * 8;
    bf16x8 af0[5], af1[5];
    #pragma unroll
    for (int kb = 0; kb < 5; ++kb) {
        af0[kb] = *(const bf16x8*)(ap0 + kb * 32);
        af1[kb] = *(const bf16x8*)(ap1 + kb * 32);
    }
    const bf16x8* b1 = (const bf16x8*)B1;
    const bf16x8* b2 = (const bf16x8*)B2;
    const bf16x8* b3 = (const bf16x8*)B3;
    f32x4 aL[2][8] = {}, aR[2][8] = {}, aS[2][2] = {};
    #pragma unroll
    for (int kb = 0; kb < 5; ++kb) {
        #pragma unroll
        for (int j = 0; j < 8; ++j) {
            bf16x8 b = b1[(kb * 16 + ch * 8 + j) * 64 + lane];
            aL[0][j] = __builtin_amdgcn_mfma_f32_16x16x32_bf16(af0[kb], b, aL[0][j], 0, 0, 0);
            aL[1][j] = __builtin_amdgcn_mfma_f32_16x16x32_bf16(af1[kb], b, aL[1][j], 0, 0, 0);
        }
        #pragma unroll
        for (int j = 0; j < 8; ++j) {
            bf16x8 b = b2[(kb * 16 + ch * 8 + j) * 64 + lane];
            aR[0][j] = __builtin_amdgcn_mfma_f32_16x16x32_bf16(af0[kb], b, aR[0][j], 0, 0, 0);
            aR[1][j] = __builtin_amdgcn_mfma_f32_16x16x32_bf16(af1[kb], b, aR[1][j], 0, 0, 0);
        }
        #pragma unroll
        for (int j = 0; j < 2; ++j) {
            bf16x8 b = b3[(kb * 4 + ch * 2 + j) * 64 + lane];
            aS[0][j] = __builtin_amdgcn_mfma_f32_16x16x32_bf16(af0[kb], b, aS[0][j], 0, 0, 0);
            aS[1][j] = __builtin_amdgcn_mfma_f32_16x16x32_bf16(af1[kb], b, aS[1][j], 0, 0, 0);
        }
    }
    const int cn = lane & 15, cq = lane >> 4;
    #pragma unroll
    for (int rt = 0; rt < 2; ++rt) {
        #pragma unroll
        for (int j = 0; j < 8; ++j) {
            int colc = (ch * 8 + j) * 16 + cn;
            float bbL = b2f(bi1[colc]);
            float bbR = b2f(bi2[colc]);
            #pragma unroll
            for (int r = 0; r < 4; ++r) {
                int grow = row0 + rt * 16 + cq * 4 + r;
                if (grow < M) {
                    o1[(size_t)grow * C1 + colc] = f2b(aL[rt][j][r] + bbL);
                    o2[(size_t)grow * C1 + colc] = f2b(aR[rt][j][r] + bbR);
                }
            }
        }
        #pragma unroll
        for (int j = 0; j < 2; ++j) {
            int colc = (ch * 2 + j) * 16 + cn;
            float bb = b2f(bi3[colc]);
            #pragma unroll
            for (int r = 0; r < 4; ++r) {
                int grow = row0 + rt * 16 + cq * 4 + r;
                if (grow < M)
                    o3[(size_t)grow * HID + colc] = f2b(aS[rt][j][r] + bb);
            }
        }
    }
}

// ---------------- fused layer-2 MFMA GEMM: xl2(64) + xr2(64), K=256 ----------------
__global__ __launch_bounds__(256) void gemm2_k(const ushort* __restrict__ A,
                                               const ushort* __restrict__ B1,
                                               const ushort* __restrict__ B2,
                                               const ushort* __restrict__ bi1,
                                               const ushort* __restrict__ bi2,
                                               ushort* __restrict__ o1,
                                               ushort* __restrict__ o2,
                                               int M) {
    const int wave = threadIdx.x >> 6;
    const int lane = threadIdx.x & 63;
    const int row0 = blockIdx.x * 64 + wave * 16;
    if (row0 >= M) return;
    int arow = row0 + (lane & 15);
    if (arow >= M) arow = M - 1;
    const ushort* aptr = A + (size_t)arow * C1 + (lane >> 4) * 8;
    const bf16x8* b1 = (const bf16x8*)B1;
    const bf16x8* b2 = (const bf16x8*)B2;
    f32x4 aL[4] = {}, aR[4] = {};
    #pragma unroll
    for (int kb = 0; kb < 8; ++kb) {
        bf16x8 af = *(const bf16x8*)(aptr + kb * 32);
        #pragma unroll
        for (int t = 0; t < 4; ++t)
            aL[t] = __builtin_amdgcn_mfma_f32_16x16x32_bf16(af, b1[(kb * 4 + t) * 64 + lane], aL[t], 0, 0, 0);
        #pragma unroll
        for (int t = 0; t < 4; ++t)
            aR[t] = __builtin_amdgcn_mfma_f32_16x16x32_bf16(af, b2[(kb * 4 + t) * 64 + lane], aR[t], 0, 0, 0);
    }
    const int cn = lane & 15, cq = lane >> 4;
    #pragma unroll
    for (int t = 0; t < 4; ++t) {
        float bbL = b2f(bi1[t * 16 + cn]);
        float bbR = b2f(bi2[t * 16 + cn]);
        #pragma unroll
        for (int r = 0; r < 4; ++r) {
            int grow = row0 + cq * 4 + r;
            if (grow < M) {
                o1[(size_t)grow * HID + t * 16 + cn] = f2b(aL[t][r] + bbL);
                o2[(size_t)grow * HID + t * 16 + cn] = f2b(aR[t][r] + bbR);
            }
        }
    }
}

// ---------------- conv1: 16 edges/trip (4 independent gather chains), 16 lanes/edge ----------------
__global__ __launch_bounds__(256) void conv1_k(const ushort* __restrict__ xl,
                                               const ushort* __restrict__ xr,
                                               const int* __restrict__ row_ptr,
                                               const int* __restrict__ col,
                                               const ushort* __restrict__ att,
                                               const ushort* __restrict__ bias1,
                                               const ushort* __restrict__ g1,
                                               const ushort* __restrict__ b1,
                                               const ushort* __restrict__ m1,
                                               const ushort* __restrict__ v1,
                                               ushort* __restrict__ h1out) {
    const int n = blockIdx.x;
    const int h = threadIdx.x >> 6;          // wave = head
    const int lane = threadIdx.x & 63;
    const int grp = lane >> 4;               // edge slot 0..3
    const int m = lane & 15;                 // channel quad
    const uint cpi = h * 16 + m;             // uint2 index within 64-uint2 row
    const uint2* xl2v = (const uint2*)xl;
    const uint2 xru = ((const uint2*)xr)[(size_t)n * 64 + cpi];
    const float xr0 = lo16(xru.x), xr1 = hi16(xru.x);
    const float xr2 = lo16(xru.y), xr3 = hi16(xru.y);
    const uint2 atu = ((const uint2*)att)[cpi];
    const float at0 = lo16(atu.x), at1 = hi16(atu.x);
    const float at2 = lo16(atu.y), at3 = hi16(atu.y);
    const int e0 = row_ptr[n], e1 = row_ptr[n + 1];
    float a0 = 0.f, a1 = 0.f, a2 = 0.f, a3 = 0.f, den = 0.f;
    uint s0_, s1_, s2_, s3_;
    {
        const int j0 = e0 + grp, j1 = e0 + 4 + grp, j2 = e0 + 8 + grp, j3 = e0 + 12 + grp;
        s0_ = (uint)col[j0 < e1 ? j0 : e1 - 1];
        s1_ = (uint)col[j1 < e1 ? j1 : e1 - 1];
        s2_ = (uint)col[j2 < e1 ? j2 : e1 - 1];
        s3_ = (uint)col[j3 < e1 ? j3 : e1 - 1];
    }
    for (int i = e0; i < e1; i += 16) {
        // 4 independent gathers in flight
        const uint2 xu0 = xl2v[(s0_ << 6) + cpi];
        const uint2 xu1 = xl2v[(s1_ << 6) + cpi];
        const uint2 xu2 = xl2v[(s2_ << 6) + cpi];
        const uint2 xu3 = xl2v[(s3_ << 6) + cpi];
        // prefetch next trip's indices
        const int j0 = i + 16 + grp, j1 = i + 20 + grp, j2 = i + 24 + grp, j3 = i + 28 + grp;
        s0_ = (uint)col[j0 < e1 ? j0 : e1 - 1];
        s1_ = (uint)col[j1 < e1 ? j1 : e1 - 1];
        s2_ = (uint)col[j2 < e1 ? j2 : e1 - 1];
        s3_ = (uint)col[j3 < e1 ? j3 : e1 - 1];
        #pragma unroll
        for (int q = 0; q < 4; ++q) {
            const uint2 xu = (q == 0) ? xu0 : (q == 1) ? xu1 : (q == 2) ? xu2 : xu3;
            const bool valid = (i + q * 4 + grp) < e1;
            const float x0 = lo16(xu.x), x1 = hi16(xu.x);
            const float x2 = lo16(xu.y), x3 = hi16(xu.y);
            float t0 = x0 + xr0; t0 = fmaxf(t0, t0 * NEG_SLOPE);
            float t1 = x1 + xr1; t1 = fmaxf(t1, t1 * NEG_SLOPE);
            float t2 = x2 + xr2; t2 = fmaxf(t2, t2 * NEG_SLOPE);
            float t3 = x3 + xr3; t3 = fmaxf(t3, t3 * NEG_SLOPE);
            float p = fmaf(t0, at0, fmaf(t1, at1, fmaf(t2, at2, t3 * at3)));
            p = row16_sum(p);
            const float w = valid ? __expf(fminf(p, 60.f)) : 0.f;
            a0 = fmaf(w, x0, a0);
            a1 = fmaf(w, x1, a1);
            a2 = fmaf(w, x2, a2);
            a3 = fmaf(w, x3, a3);
            den += w;
        }
    }
    a0 += __shfl_xor(a0, 16); a0 += __shfl_xor(a0, 32);
    a1 += __shfl_xor(a1, 16); a1 += __shfl_xor(a1, 32);
    a2 += __shfl_xor(a2, 16); a2 += __shfl_xor(a2, 32);
    a3 += __shfl_xor(a3, 16); a3 += __shfl_xor(a3, 32);
    den += __shfl_xor(den, 16); den += __shfl_xor(den, 32);
    if (lane < 16) {
        const float inv = 1.f / den;
        const uint2 biu = ((const uint2*)bias1)[cpi];
        const uint2 gu  = ((const uint2*)g1)[cpi];
        const uint2 bu  = ((const uint2*)b1)[cpi];
        const uint2 mu  = ((const uint2*)m1)[cpi];
        const uint2 vu  = ((const uint2*)v1)[cpi];
        float o0 = fmaf(a0, inv, lo16(biu.x));
        float o1 = fmaf(a1, inv, hi16(biu.x));
        float o2 = fmaf(a2, inv, lo16(biu.y));
        float o3 = fmaf(a3, inv, hi16(biu.y));
        float s0 = lo16(gu.x) * rsqrtf(lo16(vu.x) + BN_EPS);
        float s1 = hi16(gu.x) * rsqrtf(hi16(vu.x) + BN_EPS);
        float s2 = lo16(gu.y) * rsqrtf(lo16(vu.y) + BN_EPS);
        float s3 = hi16(gu.y) * rsqrtf(hi16(vu.y) + BN_EPS);
        float h0 = fmaxf((o0 - lo16(mu.x)) * s0 + lo16(bu.x), 0.f);
        float h1v = fmaxf((o1 - hi16(mu.x)) * s1 + hi16(bu.x), 0.f);
        float h2 = fmaxf((o2 - lo16(mu.y)) * s2 + lo16(bu.y), 0.f);
        float h3 = fmaxf((o3 - hi16(mu.y)) * s3 + hi16(bu.y), 0.f);
        uint2 ou;
        ou.x = (uint)f2b(h0) | ((uint)f2b(h1v) << 16);
        ou.y = (uint)f2b(h2) | ((uint)f2b(h3) << 16);
        ((uint2*)h1out)[(size_t)n * 64 + cpi] = ou;
    }
}

// ---------------- conv2 + BN2 + relu + skip + output linear ----------------
__global__ __launch_bounds__(256) void conv2_k(const ushort* __restrict__ xl,
                                               const ushort* __restrict__ xr,
                                               const ushort* __restrict__ xskip,
                                               const int* __restrict__ row_ptr,
                                               const int* __restrict__ col,
                                               const ushort* __restrict__ att2,
                                               const ushort* __restrict__ bias2,
                                               const ushort* __restrict__ g2,
                                               const ushort* __restrict__ bb2,
                                               const ushort* __restrict__ m2,
                                               const ushort* __restrict__ v2,
                                               const ushort* __restrict__ Wo,
                                               const ushort* __restrict__ bo,
                                               void* __restrict__ out,
                                               const int* __restrict__ flags) {
    const int n = blockIdx.x * 4 + (threadIdx.x >> 6);
    if (n >= N_NODES) return;
    const int lane = threadIdx.x & 63;
    const int grp = lane >> 4;
    const uint m = lane & 15;                // uint2 index within 16-uint2 row
    const uint2* xl2v = (const uint2*)xl;
    const uint2 xru = ((const uint2*)xr)[(size_t)n * 16 + m];
    const float xr0 = lo16(xru.x), xr1 = hi16(xru.x);
    const float xr2 = lo16(xru.y), xr3 = hi16(xru.y);
    const uint2 atu = ((const uint2*)att2)[m];
    const float at0 = lo16(atu.x), at1 = hi16(atu.x);
    const float at2 = lo16(atu.y), at3 = hi16(atu.y);
    const int e0 = row_ptr[n], e1 = row_ptr[n + 1];
    float a0 = 0.f, a1 = 0.f, a2 = 0.f, a3 = 0.f, den = 0.f;
    uint s0_, s1_, s2_, s3_;
    {
        const int j0 = e0 + grp, j1 = e0 + 4 + grp, j2 = e0 + 8 + grp, j3 = e0 + 12 + grp;
        s0_ = (uint)col[j0 < e1 ? j0 : e1 - 1];
        s1_ = (uint)col[j1 < e1 ? j1 : e1 - 1];
        s2_ = (uint)col[j2 < e1 ? j2 : e1 - 1];
        s3_ = (uint)col[j3 < e1 ? j3 : e1 - 1];
    }
    for (int i = e0; i < e1; i += 16) {
        const uint2 xu0 = xl2v[(s0_ << 4) + m];
        const uint2 xu1 = xl2v[(s1_ << 4) + m];
        const uint2 xu2 = xl2v[(s2_ << 4) + m];
        const uint2 xu3 = xl2v[(s3_ << 4) + m];
        const int j0 = i + 16 + grp, j1 = i + 20 + grp, j2 = i + 24 + grp, j3 = i + 28 + grp;
        s0_ = (uint)col[j0 < e1 ? j0 : e1 - 1];
        s1_ = (uint)col[j1 < e1 ? j1 : e1 - 1];
        s2_ = (uint)col[j2 < e1 ? j2 : e1 - 1];
        s3_ = (uint)col[j3 < e1 ? j3 : e1 - 1];
        #pragma unroll
        for (int q = 0; q < 4; ++q) {
            const uint2 xu = (q == 0) ? xu0 : (q == 1) ? xu1 : (q == 2) ? xu2 : xu3;
            const bool valid = (i + q * 4 + grp) < e1;
            const float x0 = lo16(xu.x), x1 = hi16(xu.x);
            const float x2 = lo16(xu.y), x3 = hi16(xu.y);
            float t0 = x0 + xr0; t0 = fmaxf(t0, t0 * NEG_SLOPE);
            float t1 = x1 + xr1; t1 = fmaxf(t1, t1 * NEG_SLOPE);
            float t2 = x2 + xr2; t2 = fmaxf(t2, t2 * NEG_SLOPE);
            float t3 = x3 + xr3; t3 = fmaxf(t3, t3 * NEG_SLOPE);
            float p = fmaf(t0, at0, fmaf(t1, at1, fmaf(t2, at2, t3 * at3)));
            p = row16_sum(p);
            const float w = valid ? __expf(fminf(p, 60.f)) : 0.f;
            a0 = fmaf(w, x0, a0);
            a1 = fmaf(w, x1, a1);
            a2 = fmaf(w, x2, a2);
            a3 = fmaf(w, x3, a3);
            den += w;
        }
    }
    a0 += __shfl_xor(a0, 16); a0 += __shfl_xor(a0, 32);
    a1 += __shfl_xor(a1, 16); a1 += __shfl_xor(a1, 32);
    a2 += __shfl_xor(a2, 16); a2 += __shfl_xor(a2, 32);
    a3 += __shfl_xor(a3, 16); a3 += __shfl_xor(a3, 32);
    den += __shfl_xor(den, 16); den += __shfl_xor(den, 32);
    if (lane < 16) {
        const float inv = 1.f / den;
        const uint2 biu = ((const uint2*)bias2)[m];
        const uint2 gu  = ((const uint2*)g2)[m];
        const uint2 bu  = ((const uint2*)bb2)[m];
        const uint2 mu  = ((const uint2*)m2)[m];
        const uint2 vu  = ((const uint2*)v2)[m];
        const uint2 sku = ((const uint2*)xskip)[(size_t)n * 16 + m];
        const uint2 wou = ((const uint2*)Wo)[m];
        float o0 = fmaf(a0, inv, lo16(biu.x));
        float o1 = fmaf(a1, inv, hi16(biu.x));
        float o2 = fmaf(a2, inv, lo16(biu.y));
        float o3 = fmaf(a3, inv, hi16(biu.y));
        float s0 = lo16(gu.x) * rsqrtf(lo16(vu.x) + BN_EPS);
        float s1 = hi16(gu.x) * rsqrtf(hi16(vu.x) + BN_EPS);
        float s2 = lo16(gu.y) * rsqrtf(lo16(vu.y) + BN_EPS);
        float s3 = hi16(gu.y) * rsqrtf(hi16(vu.y) + BN_EPS);
        float h0 = fmaxf((o0 - lo16(mu.x)) * s0 + lo16(bu.x), 0.f) + lo16(sku.x);
        float h1v = fmaxf((o1 - hi16(mu.x)) * s1 + hi16(bu.x), 0.f) + hi16(sku.x);
        float h2 = fmaxf((o2 - lo16(mu.y)) * s2 + lo16(bu.y), 0.f) + lo16(sku.y);
        float h3 = fmaxf((o3 - hi16(mu.y)) * s3 + hi16(bu.y), 0.f) + hi16(sku.y);
        float d = fmaf(h0, lo16(wou.x), fmaf(h1v, hi16(wou.x),
                  fmaf(h2, lo16(wou.y), h3 * hi16(wou.y))));
        d = row16_sum(d);
        if (m == 0) {
            float r = d + b2f(bo[0]);
            if (flags[0]) ((float*)out)[n] = r;
            else          ((ushort*)out)[n] = f2b(r);
        }
    }
}

extern "C" void kernel_launch(void* const* d_in, const int* in_sizes, int n_in,
                              void* d_out, int out_size, void* d_ws, size_t ws_size,
                              hipStream_t stream) {
    char* ws = (char*)d_ws;
    size_t off = 0;
    auto alloc = [&](size_t bytes) -> void* {
        void* p = ws + off;
        off += (bytes + 255) & ~(size_t)255;
        return p;
    };
    int*    flags   = (int*)alloc(256);
    ushort* params  = (ushort*)alloc((size_t)127617 * 2);
    ushort* x_c     = (ushort*)alloc((size_t)N_NODES * IN_DIM * 2);
    int*    row_ptr = (int*)alloc((size_t)(N_NODES + 1) * 4);
    int*    rowcur  = (int*)alloc((size_t)N_NODES * 4);
    int*    deg     = (int*)alloc((size_t)N_NODES * 4);
    int*    colbuf  = (int*)alloc((size_t)EP_EDGES * 4);
    int*    bsum    = (int*)alloc(64 * 4);
    ushort* xl1     = (ushort*)alloc((size_t)N_NODES * C1 * 2);
    ushort* xr1     = (ushort*)alloc((size_t)N_NODES * C1 * 2);
    ushort* xskip   = (ushort*)alloc((size_t)N_NODES * HID * 2);
    ushort* h1      = (ushort*)alloc((size_t)N_NODES * C1 * 2);
    ushort* xl2     = (ushort*)alloc((size_t)N_NODES * HID * 2);
    ushort* xr2     = (ushort*)alloc((size_t)N_NODES * HID * 2);
    ushort* swzWl1  = (ushort*)alloc((size_t)IN_DIM * C1 * 2);
    ushort* swzWr1  = (ushort*)alloc((size_t)IN_DIM * C1 * 2);
    ushort* swzWs   = (ushort*)alloc((size_t)IN_DIM * HID * 2);
    ushort* swzWl2  = (ushort*)alloc((size_t)C1 * HID * 2);
    ushort* swzWr2  = (ushort*)alloc((size_t)C1 * HID * 2);

    ushort* bl1c   = params + 40960;
    ushort* br1c   = params + 82176;
    ushort* att1c  = params + 82432;
    ushort* bias1c = params + 82688;
    ushort* g1c    = params + 82944;
    ushort* b1c    = params + 83200;
    ushort* m1c    = params + 83456;
    ushort* v1c    = params + 83712;
    ushort* bl2c   = params + 100352;
    ushort* br2c   = params + 116800;
    ushort* att2c  = params + 116864;
    ushort* bias2c = params + 116928;
    ushort* g2c    = params + 116992;
    ushort* b2c    = params + 117056;
    ushort* m2c    = params + 117120;
    ushort* v2c    = params + 117184;
    ushort* bsc    = params + 127488;
    ushort* Woc    = params + 127552;
    ushort* boc    = params + 127616;

    // ---- detect dtypes, canonicalize x, swizzle weights + small params ----
    detect_k<<<1, 64, 0, stream>>>((const ushort*)d_in[0], (const int*)d_in[1], flags);
    cvt_x_k<<<(N_NODES * IN_DIM + 255) / 256, 256, 0, stream>>>(d_in[0], x_c, flags, deg);

    SW2 sw;
    sw.W[0] = d_in[2];  sw.D[0] = swzWl1; sw.NT[0] = 16; sw.base[0] = 0;      // Wl1
    sw.W[1] = d_in[4];  sw.D[1] = swzWr1; sw.NT[1] = 16; sw.base[1] = 5120;   // Wr1
    sw.W[2] = d_in[22]; sw.D[2] = swzWs;  sw.NT[2] = 4;  sw.base[2] = 10240;  // Ws
    sw.W[3] = d_in[12]; sw.D[3] = swzWl2; sw.NT[3] = 4;  sw.base[3] = 11520;  // Wl2
    sw.W[4] = d_in[14]; sw.D[4] = swzWr2; sw.NT[4] = 4;  sw.base[4] = 13568;  // Wr2
    const int spidx[19] = {3,5,6,7,8,9,10,11, 13,15,16,17,18,19,20,21, 23,24, 25};
    for (int i = 0; i < 19; ++i) sw.sp[i] = d_in[spidx[i]];
    swzp_k<<<62, 256, 0, stream>>>(sw, params, flags);

    const int NB_N = (N_NODES + 255) / 256;        // 196
    const int NB_E = (EP_EDGES + 255) / 256;       // 3321
    const int NB_S = (N_NODES + 1023) / 1024;      // 49

    // ---- CSR build (reads raw edge_index) ----
    const int* ei_raw = (const int*)d_in[1];
    hist_k<<<NB_E, 256, 0, stream>>>(ei_raw, flags, deg);
    scan1_k<<<NB_S, 1024, 0, stream>>>(deg, row_ptr, bsum);
    scan2_k<<<1, 64, 0, stream>>>(bsum, NB_S);
    scan3_k<<<NB_N, 256, 0, stream>>>(row_ptr, bsum, rowcur);
    scatter_k<<<NB_E, 256, 0, stream>>>(ei_raw, flags, rowcur, colbuf);

    // ---- layer-1 linear transforms (+ skip), fused MFMA (split-N, 2 row-tiles/wave) ----
    gemm3_k<<<dim3((N_NODES + 127) / 128, 2), 256, 0, stream>>>(
        x_c, swzWl1, swzWr1, swzWs, bl1c, br1c, bsc, xl1, xr1, xskip, N_NODES);

    // ---- conv1 edge aggregation + BN1 + relu ----
    conv1_k<<<N_NODES, 256, 0, stream>>>(xl1, xr1, row_ptr, colbuf, att1c, bias1c,
                                         g1c, b1c, m1c, v1c, h1);

    // ---- layer-2 linear transforms, fused MFMA ----
    gemm2_k<<<(N_NODES + 63) / 64, 256, 0, stream>>>(h1, swzWl2, swzWr2, bl2c, br2c,
                                                     xl2, xr2, N_NODES);

    // ---- conv2 + BN2 + relu + skip + output linear ----
    conv2_k<<<(N_NODES + 3) / 4, 256, 0, stream>>>(xl2, xr2, xskip, row_ptr, colbuf,
                                                   att2c, bias2c, g2c, b2c, m2c, v2c,
                                                   Woc, boc, d_out, flags);
}